// Round 1
// baseline (377.644 us; speedup 1.0000x reference)
//
#include <hip/hip_runtime.h>

// Problem constants
#define Hn  16
#define Dh  64
#define Bb  4
#define Tn  2048
#define En  1024
#define Mn  8192           // B*T
#define N1  3072           // 3*E
#define Kn  1024           // E
#define BHT (Bb*Hn*Tn)     // 262144

typedef __attribute__((ext_vector_type(8))) short  short8;
typedef __attribute__((ext_vector_type(4))) short  short4v;
typedef __attribute__((ext_vector_type(4))) float  f32x4;
typedef __attribute__((ext_vector_type(8))) __bf16 bf16x8;

__device__ __forceinline__ float b2f(short s) {
  unsigned u = ((unsigned)(unsigned short)s) << 16;
  return __builtin_bit_cast(float, u);
}
__device__ __forceinline__ short f2b(float f) {
  unsigned u = __builtin_bit_cast(unsigned, f);
  u += 0x7fffu + ((u >> 16) & 1u);
  return (short)(u >> 16);
}
__device__ __forceinline__ f32x4 mfma16(short8 a, short8 b, f32x4 c) {
  return __builtin_amdgcn_mfma_f32_16x16x32_bf16(
      __builtin_bit_cast(bf16x8, a), __builtin_bit_cast(bf16x8, b), c, 0, 0, 0);
}
__device__ __forceinline__ void gload16(const void* g, void* l) {
  __builtin_amdgcn_global_load_lds(
      (const __attribute__((address_space(1))) unsigned int*)g,
      (__attribute__((address_space(3))) unsigned int*)l, 16, 0, 0);
}

// ---------------- cast x -> bf16 ----------------
__global__ __launch_bounds__(256) void cvt_x_kernel(const float* __restrict__ x,
                                                    short* __restrict__ xb) {
  const size_t i = ((size_t)blockIdx.x * 256 + threadIdx.x) * 8;
  f32x4 a = *(const f32x4*)&x[i];
  f32x4 b = *(const f32x4*)&x[i + 4];
  short8 o;
  o[0]=f2b(a[0]); o[1]=f2b(a[1]); o[2]=f2b(a[2]); o[3]=f2b(a[3]);
  o[4]=f2b(b[0]); o[5]=f2b(b[1]); o[6]=f2b(b[2]); o[7]=f2b(b[3]);
  *(short8*)&xb[i] = o;
}

// ---------------- transpose W [R][C] f32 -> [C][R] bf16 ----------------
__global__ __launch_bounds__(256) void transpose_w_kernel(const float* __restrict__ in,
                                                          short* __restrict__ out,
                                                          int R, int C) {
  __shared__ float tile[32][33];
  const int tid = threadIdx.x;
  const int c0 = blockIdx.x * 32, r0 = blockIdx.y * 32;
  const int lr = tid >> 3, lc = (tid & 7) * 4;
  f32x4 v = *(const f32x4*)&in[(size_t)(r0 + lr) * C + c0 + lc];
  tile[lr][lc] = v[0]; tile[lr][lc+1] = v[1]; tile[lr][lc+2] = v[2]; tile[lr][lc+3] = v[3];
  __syncthreads();
  const int oc = tid >> 3, orr = (tid & 7) * 4;
  short4v ov;
  ov[0] = f2b(tile[orr][oc]);   ov[1] = f2b(tile[orr+1][oc]);
  ov[2] = f2b(tile[orr+2][oc]); ov[3] = f2b(tile[orr+3][oc]);
  *(short4v*)&out[(size_t)(c0 + oc) * R + r0 + orr] = ov;
}

// ---------------- GEMM: C[M][N] = A[M][K] * Bt[N][K]^T + bias ----------------
// MODE 0: fp32 out to Cf.  MODE 1: bf16 scatter to q/k/v packed [B,H,T,D].
template<int MODE>
__global__ __launch_bounds__(256) void gemm_kernel(
    const short* __restrict__ A, const short* __restrict__ Bt,
    const float* __restrict__ bias, float* __restrict__ Cf,
    short* __restrict__ qo, short* __restrict__ ko2, short* __restrict__ vo,
    int N) {
  __shared__ short As[4096];
  __shared__ short Bs[4096];
  const int tid = threadIdx.x, lane = tid & 63, w = tid >> 6;
  const int rowBase = blockIdx.y * 128, colBase = blockIdx.x * 128;
  f32x4 acc[4][4] = {};
  const int srow = tid >> 2, sk = (tid & 3) << 3;
  const short* Ag = A  + (size_t)(rowBase + srow) * Kn + sk;
  const short* Bg = Bt + (size_t)(colBase + srow) * Kn + sk;
  short* AsW = As + w * 512;
  short* BsW = Bs + w * 512;
  const int ar = (w >> 1) * 64, bc = (w & 1) * 64;
  const int lg8 = (lane >> 4) * 8, lr = lane & 15;

  for (int kt = 0; kt < Kn; kt += 32) {
    __syncthreads();
    gload16(Ag + kt,            AsW);
    gload16(Ag + kt + 64 * Kn,  AsW + 2048);
    gload16(Bg + kt,            BsW);
    gload16(Bg + kt + 64 * Kn,  BsW + 2048);
    __syncthreads();
    short8 af[4], bfr[4];
#pragma unroll
    for (int m = 0; m < 4; ++m) af[m]  = *(const short8*)&As[(ar + m*16 + lr)*32 + lg8];
#pragma unroll
    for (int n = 0; n < 4; ++n) bfr[n] = *(const short8*)&Bs[(bc + n*16 + lr)*32 + lg8];
#pragma unroll
    for (int m = 0; m < 4; ++m)
#pragma unroll
      for (int n = 0; n < 4; ++n)
        acc[m][n] = mfma16(af[m], bfr[n], acc[m][n]);
  }

  const int gr0 = rowBase + ar + (lane >> 4) * 4;
  const int gc0 = colBase + bc + lr;
#pragma unroll
  for (int m = 0; m < 4; ++m) {
#pragma unroll
    for (int n = 0; n < 4; ++n) {
      const int gc = gc0 + n * 16;
      const float bb = bias[gc];
#pragma unroll
      for (int r = 0; r < 4; ++r) {
        const int gr = gr0 + m * 16 + r;
        const float v = acc[m][n][r] + bb;
        if (MODE == 0) {
          Cf[(size_t)gr * N + gc] = v;
        } else {
          const int which = gc >> 10, e = gc & 1023;
          const int hh = e >> 6, d = e & 63;
          const int bidx = gr >> 11, t = gr & 2047;
          const size_t idx = ((size_t)(bidx * Hn + hh) * Tn + t) * Dh + d;
          short* dst = (which == 0) ? qo : (which == 1) ? ko2 : vo;
          dst[idx] = f2b(v);
        }
      }
    }
  }
}

// ---------------- LayerNorm over D=64 for q (with 1/8 scale folded) and k ----------------
__global__ __launch_bounds__(256) void ln_qk_kernel(short* __restrict__ qp, short* __restrict__ kp,
                                                    const float* __restrict__ qg, const float* __restrict__ qb,
                                                    const float* __restrict__ kg, const float* __restrict__ kb) {
  const int lane = threadIdx.x & 63;
  const int rp = blockIdx.x * 4 + (threadIdx.x >> 6);
  const size_t base = (size_t)rp * 64 + lane;
  float xq = b2f(qp[base]);
  float xk = b2f(kp[base]);
  float sq = xq, sk = xk;
#pragma unroll
  for (int off = 1; off < 64; off <<= 1) { sq += __shfl_xor(sq, off); sk += __shfl_xor(sk, off); }
  const float muq = sq * (1.f/64), muk = sk * (1.f/64);
  const float dq = xq - muq, dk = xk - muk;
  float vq = dq * dq, vk = dk * dk;
#pragma unroll
  for (int off = 1; off < 64; off <<= 1) { vq += __shfl_xor(vq, off); vk += __shfl_xor(vk, off); }
  const float rq = rsqrtf(vq * (1.f/64) + 1e-5f);
  const float rk = rsqrtf(vk * (1.f/64) + 1e-5f);
  const float yq = (dq * rq * qg[lane] + qb[lane]) * 0.125f;  // fold 1/sqrt(D)
  const float yk =  dk * rk * kg[lane] + kb[lane];
  qp[base] = f2b(yq);
  kp[base] = f2b(yk);
}

// ---------------- V [bh][t][d] -> Vt [bh][d][t] ----------------
__global__ __launch_bounds__(256) void transpose_v_kernel(const short* __restrict__ vp,
                                                          short* __restrict__ vt) {
  __shared__ short tile[64][72];
  const int tid = threadIdx.x;
  const int bh = blockIdx.y, jt = blockIdx.x;
  const short* src = vp + ((size_t)bh * Tn + jt * 64) * Dh;
#pragma unroll
  for (int i = 0; i < 4; ++i) {
    const int idx = i * 1024 + tid * 4;
    short4v v = *(const short4v*)&src[idx];
    const int r = idx >> 6, c = idx & 63;
    tile[r][c] = v[0]; tile[r][c+1] = v[1]; tile[r][c+2] = v[2]; tile[r][c+3] = v[3];
  }
  __syncthreads();
  short* dst = vt + (size_t)bh * Dh * Tn + jt * 64;
#pragma unroll
  for (int i = 0; i < 4; ++i) {
    const int idx = i * 1024 + tid * 4;
    const int d = idx >> 6, t0 = idx & 63;
    short4v v;
    v[0] = tile[t0][d]; v[1] = tile[t0+1][d]; v[2] = tile[t0+2][d]; v[3] = tile[t0+3][d];
    *(short4v*)&dst[(size_t)d * Tn + t0] = v;
  }
}

// ---------------- Flash attention ----------------
// grid: (T/128, B*H), 256 threads (4 waves); each wave owns 32 q-rows.
__global__ __launch_bounds__(256) void flash_kernel(
    const short* __restrict__ qp, const short* __restrict__ kp,
    const short* __restrict__ vt, short* __restrict__ y) {
  __shared__ short Ks[4096];
  __shared__ short Vs[4096];
  __shared__ short Ps[8192];
  const int tid = threadIdx.x, lane = tid & 63, w = tid >> 6;
  const int bh = blockIdx.y, qt = blockIdx.x;
  const int lr = lane & 15, lg = lane >> 4;
  const int qrow0 = qt * 128 + w * 32;
  const short* qbase = qp + ((size_t)bh * Tn + qrow0) * Dh;

  short8 aq[2][2];
#pragma unroll
  for (int m = 0; m < 2; ++m)
#pragma unroll
    for (int kk = 0; kk < 2; ++kk)
      aq[m][kk] = *(const short8*)&qbase[(m*16 + lr)*64 + kk*32 + lg*8];

  f32x4 o[2][4] = {};
  float mrun[2][4], lrun[2][4];
#pragma unroll
  for (int m = 0; m < 2; ++m)
#pragma unroll
    for (int r = 0; r < 4; ++r) { mrun[m][r] = -3e38f; lrun[m][r] = 0.f; }

  const int srow = tid >> 3;
  const int sc = (tid & 7) * 8;
  short* KsW = Ks + w * 512;
  short* VsW = Vs + w * 512;
  short* Pw  = Ps + w * 2048;
  const short* kb = kp + (size_t)bh * Tn * Dh;
  const short* vb = vt + (size_t)bh * Dh * Tn;

  for (int j = 0; j < Tn / 64; ++j) {
    __syncthreads();
#pragma unroll
    for (int i = 0; i < 2; ++i) {
      const int row = i * 32 + srow;
      const int scs = sc ^ ((row & 7) << 3);   // pre-swizzled global source (T2/m173)
      gload16(kb + (size_t)(j*64 + row) * Dh + scs, KsW + i * 2048);
      gload16(vb + (size_t)row * Tn + j * 64 + scs, VsW + i * 2048);
    }
    __syncthreads();

    // S = Q K^T  (C-layout: col=k=lr+16n, row=q=lg*4+r+16m)
    short8 bk[4][2];
#pragma unroll
    for (int n = 0; n < 4; ++n)
#pragma unroll
      for (int kk = 0; kk < 2; ++kk) {
        const int row = n * 16 + lr;
        bk[n][kk] = *(const short8*)&Ks[row*64 + ((kk*32 + lg*8) ^ ((row & 7) << 3))];
      }
    f32x4 s[2][4] = {};
#pragma unroll
    for (int m = 0; m < 2; ++m)
#pragma unroll
      for (int n = 0; n < 4; ++n) {
        s[m][n] = mfma16(aq[m][0], bk[n][0], s[m][n]);
        s[m][n] = mfma16(aq[m][1], bk[n][1], s[m][n]);
      }

    // online softmax
    float pm[2][4];
#pragma unroll
    for (int m = 0; m < 2; ++m)
#pragma unroll
      for (int r = 0; r < 4; ++r)
        pm[m][r] = fmaxf(fmaxf(s[m][0][r], s[m][1][r]), fmaxf(s[m][2][r], s[m][3][r]));
#pragma unroll
    for (int off = 1; off < 16; off <<= 1)
#pragma unroll
      for (int m = 0; m < 2; ++m)
#pragma unroll
        for (int r = 0; r < 4; ++r)
          pm[m][r] = fmaxf(pm[m][r], __shfl_xor(pm[m][r], off));
    float corr[2][4];
#pragma unroll
    for (int m = 0; m < 2; ++m)
#pragma unroll
      for (int r = 0; r < 4; ++r) {
        const float mn = fmaxf(mrun[m][r], pm[m][r]);
        corr[m][r] = __expf(mrun[m][r] - mn);
        mrun[m][r] = mn;
      }
    float rs[2][4] = {};
#pragma unroll
    for (int m = 0; m < 2; ++m)
#pragma unroll
      for (int n = 0; n < 4; ++n)
#pragma unroll
        for (int r = 0; r < 4; ++r) {
          const float p = __expf(s[m][n][r] - mrun[m][r]);
          s[m][n][r] = p;
          rs[m][r] += p;
        }
#pragma unroll
    for (int off = 1; off < 16; off <<= 1)
#pragma unroll
      for (int m = 0; m < 2; ++m)
#pragma unroll
        for (int r = 0; r < 4; ++r)
          rs[m][r] += __shfl_xor(rs[m][r], off);
#pragma unroll
    for (int m = 0; m < 2; ++m)
#pragma unroll
      for (int r = 0; r < 4; ++r)
        lrun[m][r] = lrun[m][r] * corr[m][r] + rs[m][r];
#pragma unroll
    for (int m = 0; m < 2; ++m)
#pragma unroll
      for (int dn = 0; dn < 4; ++dn)
#pragma unroll
        for (int r = 0; r < 4; ++r)
          o[m][dn][r] *= corr[m][r];

    // P -> per-wave LDS (bf16, swizzled rows)
#pragma unroll
    for (int m = 0; m < 2; ++m)
#pragma unroll
      for (int n = 0; n < 4; ++n)
#pragma unroll
        for (int r = 0; r < 4; ++r) {
          const int q = m*16 + lg*4 + r;
          const int k = n*16 + lr;
          Pw[q*64 + (k ^ ((q & 7) << 3))] = f2b(s[m][n][r]);
        }

    // O += P V
    short8 pa[2][2], bv[4][2];
#pragma unroll
    for (int m = 0; m < 2; ++m)
#pragma unroll
      for (int kk = 0; kk < 2; ++kk) {
        const int q = m*16 + lr;
        pa[m][kk] = *(const short8*)&Pw[q*64 + ((kk*32 + lg*8) ^ ((q & 7) << 3))];
      }
#pragma unroll
    for (int dn = 0; dn < 4; ++dn)
#pragma unroll
      for (int kk = 0; kk < 2; ++kk) {
        const int row = dn * 16 + lr;
        bv[dn][kk] = *(const short8*)&Vs[row*64 + ((kk*32 + lg*8) ^ ((row & 7) << 3))];
      }
#pragma unroll
    for (int m = 0; m < 2; ++m)
#pragma unroll
      for (int dn = 0; dn < 4; ++dn) {
        o[m][dn] = mfma16(pa[m][0], bv[dn][0], o[m][dn]);
        o[m][dn] = mfma16(pa[m][1], bv[dn][1], o[m][dn]);
      }
  }

  // normalize + store y[B][T][E] bf16
  const int b = bh >> 4, hh = bh & 15;
  short* yb = y + (size_t)b * Tn * En + hh * 64;
#pragma unroll
  for (int m = 0; m < 2; ++m)
#pragma unroll
    for (int r = 0; r < 4; ++r) {
      const float rl = 1.0f / lrun[m][r];
      const int t = qrow0 + m*16 + lg*4 + r;
#pragma unroll
      for (int dn = 0; dn < 4; ++dn) {
        const int d = dn*16 + lr;
        yb[(size_t)t * En + d] = f2b(o[m][dn][r] * rl);
      }
    }
}

extern "C" void kernel_launch(void* const* d_in, const int* in_sizes, int n_in,
                              void* d_out, int out_size, void* d_ws, size_t ws_size,
                              hipStream_t stream) {
  const float* x     = (const float*)d_in[0];
  const float* Wqkv  = (const float*)d_in[1];
  const float* bqkv  = (const float*)d_in[2];
  const float* qg    = (const float*)d_in[3];
  const float* qb    = (const float*)d_in[4];
  const float* kg    = (const float*)d_in[5];
  const float* kb    = (const float*)d_in[6];
  const float* Wproj = (const float*)d_in[7];
  const float* bproj = (const float*)d_in[8];
  float* out = (float*)d_out;

  char* p = (char*)d_ws;
  short* xb     = (short*)p; p += (size_t)Mn * Kn * 2;
  short* wqkvT  = (short*)p; p += (size_t)N1 * Kn * 2;
  short* wprojT = (short*)p; p += (size_t)En * Kn * 2;
  short* qp     = (short*)p; p += (size_t)Mn * Kn * 2;
  short* kp     = (short*)p; p += (size_t)Mn * Kn * 2;
  short* vp     = (short*)p; p += (size_t)Mn * Kn * 2;
  short* vtb    = (short*)p; p += (size_t)Mn * Kn * 2;
  short* yb     = (short*)p; p += (size_t)Mn * Kn * 2;

  cvt_x_kernel<<<Mn * Kn / (256 * 8), 256, 0, stream>>>(x, xb);
  transpose_w_kernel<<<dim3(N1 / 32, Kn / 32), 256, 0, stream>>>(Wqkv, wqkvT, Kn, N1);
  transpose_w_kernel<<<dim3(En / 32, Kn / 32), 256, 0, stream>>>(Wproj, wprojT, Kn, En);
  gemm_kernel<1><<<dim3(N1 / 128, Mn / 128), 256, 0, stream>>>(
      xb, wqkvT, bqkv, nullptr, qp, kp, vp, N1);
  ln_qk_kernel<<<BHT / 4, 256, 0, stream>>>(qp, kp, qg, qb, kg, kb);
  transpose_v_kernel<<<dim3(Tn / 64, Bb * Hn), 256, 0, stream>>>(vp, vtb);
  flash_kernel<<<dim3(Tn / 128, Bb * Hn), 256, 0, stream>>>(qp, kp, vtb, yb);
  gemm_kernel<0><<<dim3(En / 128, Mn / 128), 256, 0, stream>>>(
      yb, wprojT, bproj, out, nullptr, nullptr, nullptr, En);
}

// Round 4
// 291.600 us; speedup vs baseline: 1.2951x; 1.2951x over previous
//
#include <hip/hip_runtime.h>

// Problem constants
#define Hn  16
#define Dh  64
#define Bb  4
#define Tn  2048
#define En  1024
#define Mn  8192           // B*T
#define N1  3072           // 3*E
#define Kn  1024           // E
#define BHT (Bb*Hn*Tn)     // 262144

typedef __attribute__((ext_vector_type(8)))  short  short8;
typedef __attribute__((ext_vector_type(4)))  short  short4v;
typedef __attribute__((ext_vector_type(4)))  float  f32x4;
typedef __attribute__((ext_vector_type(8)))  __bf16 bf16x8;

__device__ __forceinline__ float b2f(short s) {
  unsigned u = ((unsigned)(unsigned short)s) << 16;
  return __builtin_bit_cast(float, u);
}
__device__ __forceinline__ short f2b(float f) {
  unsigned u = __builtin_bit_cast(unsigned, f);
  u += 0x7fffu + ((u >> 16) & 1u);
  return (short)(u >> 16);
}
__device__ __forceinline__ f32x4 mfma16(short8 a, short8 b, f32x4 c) {
  return __builtin_amdgcn_mfma_f32_16x16x32_bf16(
      __builtin_bit_cast(bf16x8, a), __builtin_bit_cast(bf16x8, b), c, 0, 0, 0);
}
__device__ __forceinline__ void gload16(const void* g, void* l) {
  __builtin_amdgcn_global_load_lds(
      (const __attribute__((address_space(1))) unsigned int*)g,
      (__attribute__((address_space(3))) unsigned int*)l, 16, 0, 0);
}

// ---------------- cast x -> bf16 ----------------
__global__ __launch_bounds__(256) void cvt_x_kernel(const float* __restrict__ x,
                                                    short* __restrict__ xb) {
  const size_t i = ((size_t)blockIdx.x * 256 + threadIdx.x) * 8;
  f32x4 a = *(const f32x4*)&x[i];
  f32x4 b = *(const f32x4*)&x[i + 4];
  short8 o;
  o[0]=f2b(a[0]); o[1]=f2b(a[1]); o[2]=f2b(a[2]); o[3]=f2b(a[3]);
  o[4]=f2b(b[0]); o[5]=f2b(b[1]); o[6]=f2b(b[2]); o[7]=f2b(b[3]);
  *(short8*)&xb[i] = o;
}

// ---------------- transpose W [R][C] f32 -> [C][R] bf16 ----------------
__global__ __launch_bounds__(256) void transpose_w_kernel(const float* __restrict__ in,
                                                          short* __restrict__ out,
                                                          int R, int C) {
  __shared__ float tile[32][33];
  const int tid = threadIdx.x;
  const int c0 = blockIdx.x * 32, r0 = blockIdx.y * 32;
  const int lr = tid >> 3, lc = (tid & 7) * 4;
  f32x4 v = *(const f32x4*)&in[(size_t)(r0 + lr) * C + c0 + lc];
  tile[lr][lc] = v[0]; tile[lr][lc+1] = v[1]; tile[lr][lc+2] = v[2]; tile[lr][lc+3] = v[3];
  __syncthreads();
  const int oc = tid >> 3, orr = (tid & 7) * 4;
  short4v ov;
  ov[0] = f2b(tile[orr][oc]);   ov[1] = f2b(tile[orr+1][oc]);
  ov[2] = f2b(tile[orr+2][oc]); ov[3] = f2b(tile[orr+3][oc]);
  *(short4v*)&out[(size_t)(c0 + oc) * R + r0 + orr] = ov;
}

// ---------------- GEMM: C[M][N] = A[M][K] * Bt[N][K]^T + bias ----------------
template<int MODE>
__global__ __launch_bounds__(256) void gemm_kernel(
    const short* __restrict__ A, const short* __restrict__ Bt,
    const float* __restrict__ bias, float* __restrict__ Cf,
    short* __restrict__ qo, short* __restrict__ ko2, short* __restrict__ vo,
    int N) {
  __shared__ short As[4096];
  __shared__ short Bs[4096];
  const int tid = threadIdx.x, lane = tid & 63, w = tid >> 6;
  const int rowBase = blockIdx.y * 128, colBase = blockIdx.x * 128;
  f32x4 acc[4][4] = {};
  const int srow = tid >> 2, sk = (tid & 3) << 3;
  const short* Ag = A  + (size_t)(rowBase + srow) * Kn + sk;
  const short* Bg = Bt + (size_t)(colBase + srow) * Kn + sk;
  short* AsW = As + w * 512;
  short* BsW = Bs + w * 512;
  const int ar = (w >> 1) * 64, bc = (w & 1) * 64;
  const int lg8 = (lane >> 4) * 8, lr = lane & 15;

  for (int kt = 0; kt < Kn; kt += 32) {
    __syncthreads();
    gload16(Ag + kt,            AsW);
    gload16(Ag + kt + 64 * Kn,  AsW + 2048);
    gload16(Bg + kt,            BsW);
    gload16(Bg + kt + 64 * Kn,  BsW + 2048);
    __syncthreads();
    short8 af[4], bfr[4];
#pragma unroll
    for (int m = 0; m < 4; ++m) af[m]  = *(const short8*)&As[(ar + m*16 + lr)*32 + lg8];
#pragma unroll
    for (int n = 0; n < 4; ++n) bfr[n] = *(const short8*)&Bs[(bc + n*16 + lr)*32 + lg8];
#pragma unroll
    for (int m = 0; m < 4; ++m)
#pragma unroll
      for (int n = 0; n < 4; ++n)
        acc[m][n] = mfma16(af[m], bfr[n], acc[m][n]);
  }

  const int gr0 = rowBase + ar + (lane >> 4) * 4;
  const int gc0 = colBase + bc + lr;
#pragma unroll
  for (int m = 0; m < 4; ++m) {
#pragma unroll
    for (int n = 0; n < 4; ++n) {
      const int gc = gc0 + n * 16;
      const float bb = bias[gc];
#pragma unroll
      for (int r = 0; r < 4; ++r) {
        const int gr = gr0 + m * 16 + r;
        const float v = acc[m][n][r] + bb;
        if (MODE == 0) {
          Cf[(size_t)gr * N + gc] = v;
        } else {
          const int which = gc >> 10, e = gc & 1023;
          const int hh = e >> 6, d = e & 63;
          const int bidx = gr >> 11, t = gr & 2047;
          const size_t idx = ((size_t)(bidx * Hn + hh) * Tn + t) * Dh + d;
          short* dst = (which == 0) ? qo : (which == 1) ? ko2 : vo;
          dst[idx] = f2b(v);
        }
      }
    }
  }
}

// ---------------- LayerNorm over D=64; q gets 1/sqrt(D)*log2(e) folded ----------------
__global__ __launch_bounds__(256) void ln_qk_kernel(short* __restrict__ qp, short* __restrict__ kp,
                                                    const float* __restrict__ qg, const float* __restrict__ qb,
                                                    const float* __restrict__ kg, const float* __restrict__ kb) {
  const int lane = threadIdx.x & 63;
  const int rp = blockIdx.x * 4 + (threadIdx.x >> 6);
  const size_t base = (size_t)rp * 64 + lane;
  float xq = b2f(qp[base]);
  float xk = b2f(kp[base]);
  float sq = xq, sk = xk;
#pragma unroll
  for (int off = 1; off < 64; off <<= 1) { sq += __shfl_xor(sq, off); sk += __shfl_xor(sk, off); }
  const float muq = sq * (1.f/64), muk = sk * (1.f/64);
  const float dq = xq - muq, dk = xk - muk;
  float vq = dq * dq, vk = dk * dk;
#pragma unroll
  for (int off = 1; off < 64; off <<= 1) { vq += __shfl_xor(vq, off); vk += __shfl_xor(vk, off); }
  const float rq = rsqrtf(vq * (1.f/64) + 1e-5f);
  const float rk = rsqrtf(vk * (1.f/64) + 1e-5f);
  // fold 1/sqrt(D)=0.125 and log2(e): attention softmax runs in exp2 domain
  const float yq = (dq * rq * qg[lane] + qb[lane]) * (0.125f * 1.44269504088896f);
  const float yk =  dk * rk * kg[lane] + kb[lane];
  qp[base] = f2b(yq);
  kp[base] = f2b(yk);
}

// ---------------- V [bh][t][d] -> Vt [bh][d][t] ----------------
__global__ __launch_bounds__(256) void transpose_v_kernel(const short* __restrict__ vp,
                                                          short* __restrict__ vt) {
  __shared__ short tile[64][72];
  const int tid = threadIdx.x;
  const int bh = blockIdx.y, jt = blockIdx.x;
  const short* src = vp + ((size_t)bh * Tn + jt * 64) * Dh;
#pragma unroll
  for (int i = 0; i < 4; ++i) {
    const int idx = i * 1024 + tid * 4;
    short4v v = *(const short4v*)&src[idx];
    const int r = idx >> 6, c = idx & 63;
    tile[r][c] = v[0]; tile[r][c+1] = v[1]; tile[r][c+2] = v[2]; tile[r][c+3] = v[3];
  }
  __syncthreads();
  short* dst = vt + (size_t)bh * Dh * Tn + jt * 64;
#pragma unroll
  for (int i = 0; i < 4; ++i) {
    const int idx = i * 1024 + tid * 4;
    const int d = idx >> 6, t0 = idx & 63;
    short4v v;
    v[0] = tile[t0][d]; v[1] = tile[t0+1][d]; v[2] = tile[t0+2][d]; v[3] = tile[t0+3][d];
    *(short4v*)&dst[(size_t)d * Tn + t0] = v;
  }
}

// ---------------- Flash attention (round-1-proven 16x16 structure) ----------------
// 1024 blocks (XCD-swizzled -> (bh,qt)), 4 waves, 32 q-rows/wave, KVBLK=64.
// New vs round 1 (all layout-free): exp2 domain, defer-max (no per-tile max tree
// or O-rescale), deferred row-sum (per-lane partials, one tree in epilogue),
// truncating P-store with bias-cancelling lpart, dbuf K/V staging, setprio.
__global__ __launch_bounds__(256) void flash_kernel(
    const short* __restrict__ qp, const short* __restrict__ kp,
    const short* __restrict__ vt, short* __restrict__ y) {
  __shared__ short Ks[2][4096];   // [buf][64 keys][64 d]
  __shared__ short Vs[2][4096];   // [buf][64 d][64 keys]
  __shared__ short Ps[8192];      // per-wave 2048 shorts: [32 q][64 k]
  const int tid = threadIdx.x, lane = tid & 63, w = tid >> 6;
  const int lr = lane & 15, lg = lane >> 4;

  // XCD swizzle (bijective): XCD x handles bh in [8x,8x+8), 16 q-tiles each
  const int j0 = blockIdx.x;
  const int xcd = j0 & 7, kk0 = j0 >> 3;
  const int bh = 8 * xcd + (kk0 & 7), qt = kk0 >> 3;

  const int qrow0 = qt * 128 + w * 32;
  const short* qbase = qp + ((size_t)bh * Tn + qrow0) * Dh;

  short8 aq[2][2];
#pragma unroll
  for (int m = 0; m < 2; ++m)
#pragma unroll
    for (int kk = 0; kk < 2; ++kk)
      aq[m][kk] = *(const short8*)&qbase[(m*16 + lr)*64 + kk*32 + lg*8];

  f32x4 o[2][4] = {};
  float mrow[2][4], lpart[2][4];
#pragma unroll
  for (int m = 0; m < 2; ++m)
#pragma unroll
    for (int r = 0; r < 4; ++r) { mrow[m][r] = -3e38f; lpart[m][r] = 0.f; }

  const int srow = tid >> 3;         // 0..31
  const int sc = (tid & 7) * 8;      // shorts
  short* Pw = Ps + w * 2048;
  const short* kb = kp + (size_t)bh * Tn * Dh;
  const short* vb = vt + (size_t)bh * Dh * Tn;

#define STAGE(jt, bsel)                                                   \
  {                                                                       \
    _Pragma("unroll")                                                     \
    for (int i = 0; i < 2; ++i) {                                         \
      const int row = i * 32 + srow;                                      \
      const int scs = sc ^ ((row & 7) << 3);                              \
      gload16(kb + (size_t)((jt) * 64 + row) * Dh + scs,                  \
              &Ks[bsel][w * 512 + i * 2048]);                             \
      gload16(vb + (size_t)row * Tn + (jt) * 64 + scs,                    \
              &Vs[bsel][w * 512 + i * 2048]);                             \
    }                                                                     \
  }

  STAGE(0, 0);
  __syncthreads();

  for (int j = 0; j < Tn / 64; ++j) {
    const int cur = j & 1;
    if (j + 1 < Tn / 64) STAGE(j + 1, cur ^ 1);

    // S = Q K^T  (C: row=q=lg*4+r+16m, col=key=lr+16n)
    short8 bk[4][2];
#pragma unroll
    for (int n = 0; n < 4; ++n)
#pragma unroll
      for (int kk = 0; kk < 2; ++kk) {
        const int row = n * 16 + lr;
        bk[n][kk] = *(const short8*)&Ks[cur][row*64 + ((kk*32 + lg*8) ^ ((row & 7) << 3))];
      }
    f32x4 s[2][4] = {};
    __builtin_amdgcn_s_setprio(1);
#pragma unroll
    for (int m = 0; m < 2; ++m)
#pragma unroll
      for (int n = 0; n < 4; ++n) {
        s[m][n] = mfma16(aq[m][0], bk[n][0], s[m][n]);
        s[m][n] = mfma16(aq[m][1], bk[n][1], s[m][n]);
      }
    __builtin_amdgcn_s_setprio(0);

    // defer-max: per-lane partial max vs stale row max
    float pm[2][4];
#pragma unroll
    for (int m = 0; m < 2; ++m)
#pragma unroll
      for (int r = 0; r < 4; ++r)
        pm[m][r] = fmaxf(fmaxf(s[m][0][r], s[m][1][r]), fmaxf(s[m][2][r], s[m][3][r]));
    int ok = 1;
#pragma unroll
    for (int m = 0; m < 2; ++m)
#pragma unroll
      for (int r = 0; r < 4; ++r)
        ok &= (pm[m][r] <= mrow[m][r] + 11.0f) ? 1 : 0;
    if (!__all(ok)) {
      float tm[2][4];
#pragma unroll
      for (int m = 0; m < 2; ++m)
#pragma unroll
        for (int r = 0; r < 4; ++r) tm[m][r] = pm[m][r];
#pragma unroll
      for (int off = 1; off < 16; off <<= 1)
#pragma unroll
        for (int m = 0; m < 2; ++m)
#pragma unroll
          for (int r = 0; r < 4; ++r)
            tm[m][r] = fmaxf(tm[m][r], __shfl_xor(tm[m][r], off));
#pragma unroll
      for (int m = 0; m < 2; ++m)
#pragma unroll
        for (int r = 0; r < 4; ++r) {
          const float mn = fmaxf(mrow[m][r], tm[m][r]);
          const float corr = __builtin_amdgcn_exp2f(mrow[m][r] - mn);
          lpart[m][r] *= corr;
#pragma unroll
          for (int dn = 0; dn < 4; ++dn) o[m][dn][r] *= corr;
          mrow[m][r] = mn;
        }
    }

    // exp2, accumulate truncated partials, write P (truncated bf16)
#pragma unroll
    for (int m = 0; m < 2; ++m)
#pragma unroll
      for (int n = 0; n < 4; ++n)
#pragma unroll
        for (int r = 0; r < 4; ++r) {
          const float p = __builtin_amdgcn_exp2f(s[m][n][r] - mrow[m][r]);
          const unsigned u = __builtin_bit_cast(unsigned, p);
          lpart[m][r] += __builtin_bit_cast(float, u & 0xffff0000u);
          const int q = m*16 + lg*4 + r;
          const int k = n*16 + lr;
          Pw[q*64 + (k ^ ((q & 7) << 3))] = (short)(u >> 16);
        }

    // O += P V
    short8 pa[2][2], bv[4][2];
#pragma unroll
    for (int m = 0; m < 2; ++m)
#pragma unroll
      for (int kk = 0; kk < 2; ++kk) {
        const int q = m*16 + lr;
        pa[m][kk] = *(const short8*)&Pw[q*64 + ((kk*32 + lg*8) ^ ((q & 7) << 3))];
      }
#pragma unroll
    for (int dn = 0; dn < 4; ++dn)
#pragma unroll
      for (int kk = 0; kk < 2; ++kk) {
        const int row = dn * 16 + lr;
        bv[dn][kk] = *(const short8*)&Vs[cur][row*64 + ((kk*32 + lg*8) ^ ((row & 7) << 3))];
      }
    __builtin_amdgcn_s_setprio(1);
#pragma unroll
    for (int m = 0; m < 2; ++m)
#pragma unroll
      for (int dn = 0; dn < 4; ++dn) {
        o[m][dn] = mfma16(pa[m][0], bv[dn][0], o[m][dn]);
        o[m][dn] = mfma16(pa[m][1], bv[dn][1], o[m][dn]);
      }
    __builtin_amdgcn_s_setprio(0);

    __syncthreads();
  }
#undef STAGE

  // one row-sum tree for the whole kernel
#pragma unroll
  for (int off = 1; off < 16; off <<= 1)
#pragma unroll
    for (int m = 0; m < 2; ++m)
#pragma unroll
      for (int r = 0; r < 4; ++r)
        lpart[m][r] += __shfl_xor(lpart[m][r], off);

  // normalize + store y[B][T][E] bf16
  const int b = bh >> 4, hh = bh & 15;
  short* yb = y + (size_t)b * Tn * En + hh * 64;
#pragma unroll
  for (int m = 0; m < 2; ++m)
#pragma unroll
    for (int r = 0; r < 4; ++r) {
      const float rl = 1.0f / lpart[m][r];
      const int t = qrow0 + m*16 + lg*4 + r;
#pragma unroll
      for (int dn = 0; dn < 4; ++dn) {
        const int d = dn*16 + lr;
        yb[(size_t)t * En + d] = f2b(o[m][dn][r] * rl);
      }
    }
}

extern "C" void kernel_launch(void* const* d_in, const int* in_sizes, int n_in,
                              void* d_out, int out_size, void* d_ws, size_t ws_size,
                              hipStream_t stream) {
  const float* x     = (const float*)d_in[0];
  const float* Wqkv  = (const float*)d_in[1];
  const float* bqkv  = (const float*)d_in[2];
  const float* qg    = (const float*)d_in[3];
  const float* qb    = (const float*)d_in[4];
  const float* kg    = (const float*)d_in[5];
  const float* kb    = (const float*)d_in[6];
  const float* Wproj = (const float*)d_in[7];
  const float* bproj = (const float*)d_in[8];
  float* out = (float*)d_out;

  char* p = (char*)d_ws;
  short* xb     = (short*)p; p += (size_t)Mn * Kn * 2;
  short* wqkvT  = (short*)p; p += (size_t)N1 * Kn * 2;
  short* wprojT = (short*)p; p += (size_t)En * Kn * 2;
  short* qp     = (short*)p; p += (size_t)Mn * Kn * 2;
  short* kp     = (short*)p; p += (size_t)Mn * Kn * 2;
  short* vp     = (short*)p; p += (size_t)Mn * Kn * 2;
  short* vtb    = (short*)p; p += (size_t)Mn * Kn * 2;
  short* yb     = (short*)p; p += (size_t)Mn * Kn * 2;

  cvt_x_kernel<<<Mn * Kn / (256 * 8), 256, 0, stream>>>(x, xb);
  transpose_w_kernel<<<dim3(N1 / 32, Kn / 32), 256, 0, stream>>>(Wqkv, wqkvT, Kn, N1);
  transpose_w_kernel<<<dim3(En / 32, Kn / 32), 256, 0, stream>>>(Wproj, wprojT, Kn, En);
  gemm_kernel<1><<<dim3(N1 / 128, Mn / 128), 256, 0, stream>>>(
      xb, wqkvT, bqkv, nullptr, qp, kp, vp, N1);
  ln_qk_kernel<<<BHT / 4, 256, 0, stream>>>(qp, kp, qg, qb, kg, kb);
  transpose_v_kernel<<<dim3(Tn / 64, Bb * Hn), 256, 0, stream>>>(vp, vtb);
  flash_kernel<<<1024, 256, 0, stream>>>(qp, kp, vtb, yb);
  gemm_kernel<0><<<dim3(En / 128, Mn / 128), 256, 0, stream>>>(
      yb, wprojT, bproj, out, nullptr, nullptr, nullptr, En);
}